// Round 2
// baseline (973.577 us; speedup 1.0000x reference)
//
#include <hip/hip_runtime.h>
#include <hip/hip_bf16.h>
#include <stdint.h>

using u16 = unsigned short;

#define HDIM 1024
#define NTOK 16384
#define BM 128
#define BN 128
#define BK 32

typedef __attribute__((ext_vector_type(4))) float f32x4;
typedef __attribute__((ext_vector_type(8))) short bf16x8;
typedef __attribute__((ext_vector_type(4))) float fvec4;
typedef __attribute__((ext_vector_type(4))) u16 us4;

typedef __attribute__((address_space(3))) uint8_t lds_u8;
typedef const __attribute__((address_space(1))) uint8_t gl_u8;

static __device__ __forceinline__ u16 f2bf(float f) {
    union { float f; uint32_t u; } a; a.f = f;
    uint32_t u = a.u;
    return (u16)((u + 0x7fffu + ((u >> 16) & 1u)) >> 16);
}
static __device__ __forceinline__ float bf2f(u16 h) {
    union { uint32_t u; float f; } a; a.u = ((uint32_t)h) << 16;
    return a.f;
}

// fp32 -> (bf16 hi, bf16 lo) split, vectorized x4, grid-stride.
__global__ void convert_split_kernel(const float* __restrict__ src,
                                     u16* __restrict__ hi,
                                     u16* __restrict__ lo, int n4) {
    int stride = gridDim.x * blockDim.x;
    for (int i = blockIdx.x * blockDim.x + threadIdx.x; i < n4; i += stride) {
        fvec4 v = ((const fvec4*)src)[i];
        us4 hv, lv;
#pragma unroll
        for (int j = 0; j < 4; ++j) {
            u16 h = f2bf(v[j]);
            hv[j] = h;
            lv[j] = f2bf(v[j] - bf2f(h));
        }
        ((us4*)hi)[i] = hv;
        ((us4*)lo)[i] = lv;
    }
}

// All six HxH weight splits in one launch; blockIdx.y selects the matrix.
__global__ void convert_weights_kernel(
    const float* __restrict__ wz, const float* __restrict__ uz,
    const float* __restrict__ wr, const float* __restrict__ ur,
    const float* __restrict__ wh, const float* __restrict__ uh,
    u16* __restrict__ dst_hi_base, u16* __restrict__ dst_lo_base_unused,
    int n4) {
    const float* srcs[6] = {wz, uz, wr, ur, wh, uh};
    const int m = blockIdx.y;
    const float* src = srcs[m];
    // layout in ws: per matrix m, hi at base + (2m)*HH, lo at base + (2m+1)*HH
    const size_t HH = (size_t)HDIM * HDIM;
    u16* hi = dst_hi_base + (size_t)(2 * m) * HH;
    u16* lo = dst_hi_base + (size_t)(2 * m + 1) * HH;
    int stride = gridDim.x * blockDim.x;
    for (int i = blockIdx.x * blockDim.x + threadIdx.x; i < n4; i += stride) {
        fvec4 v = ((const fvec4*)src)[i];
        us4 hv, lv;
#pragma unroll
        for (int j = 0; j < 4; ++j) {
            u16 h = f2bf(v[j]);
            hv[j] = h;
            lv[j] = f2bf(v[j] - bf2f(h));
        }
        ((us4*)hi)[i] = hv;
        ((us4*)lo)[i] = lv;
    }
}

// Stage one [128][32] bf16 tile (8KB) into LDS via global_load_lds width=16.
// LDS dest is wave-uniform base + lane*16 (lane-contiguous, rule m104/m108).
// Bank-conflict fix via SOURCE pre-swizzle (rule #21): LDS stays linear,
// the ds_read applies the same XOR -> net identity on data, banks spread.
static __device__ __forceinline__ void stage_tile(const u16* __restrict__ g,
                                                  u16* lds_base, int t) {
#pragma unroll
    for (int i = 0; i < 2; ++i) {
        int c = t + i * 256;
        int row = c >> 2;         // 0..127
        int cs = c & 3;           // 16B chunk within row
        int scs = cs ^ ((row >> 1) & 3);
        const u16* src = g + (size_t)row * HDIM + scs * 8;
        __builtin_amdgcn_global_load_lds((gl_u8*)src, (lds_u8*)(lds_base + c * 8), 16, 0, 0);
    }
}

// One kernel, three modes:
//  mode 0: z = sigmoid(update@wz.T + hidden@uz.T + bz)      -> zbuf (=d_out)
//  mode 1: r = sigmoid(update@wr.T + hidden@ur.T + br); rh=r*hidden -> rh hi/lo
//  mode 2: h = tanh(update@wh.T + rh@uh.T + bh); out = (1-z)*hidden + z*h
// Each is one K=2048 GEMM (concat along K), split-bf16: 3 MFMAs per frag pair.
__launch_bounds__(256, 2)
__global__ void gru_gemm_kernel(
    const u16* __restrict__ up_hi, const u16* __restrict__ up_lo,
    const u16* __restrict__ hid_hi, const u16* __restrict__ hid_lo,
    const u16* __restrict__ rh_hi_in, const u16* __restrict__ rh_lo_in,
    const u16* __restrict__ wb,   // weight hi/lo block base (12 HxH arrays)
    const float* __restrict__ bz, const float* __restrict__ br,
    const float* __restrict__ bh,
    const float* __restrict__ hidden,
    float* zbuf, u16* rh_hi_out, u16* rh_lo_out, float* out, int phase) {

    const int mode = (phase == 0) ? (int)blockIdx.z : 2;
    const size_t HH = (size_t)HDIM * HDIM;

    // weight layout: [wz_hi, wz_lo, uz_hi, uz_lo, wr_hi, wr_lo, ur_hi, ur_lo,
    //                 wh_hi, wh_lo, uh_hi, uh_lo], each HH elems
    const u16 *A2h, *A2l, *B1h, *B1l, *B2h, *B2l;
    const float* bias;
    if (mode == 0) {
        A2h = hid_hi; A2l = hid_lo;
        B1h = wb + 0 * HH; B1l = wb + 1 * HH; B2h = wb + 2 * HH; B2l = wb + 3 * HH;
        bias = bz;
    } else if (mode == 1) {
        A2h = hid_hi; A2l = hid_lo;
        B1h = wb + 4 * HH; B1l = wb + 5 * HH; B2h = wb + 6 * HH; B2l = wb + 7 * HH;
        bias = br;
    } else {
        A2h = rh_hi_in; A2l = rh_lo_in;
        B1h = wb + 8 * HH; B1l = wb + 9 * HH; B2h = wb + 10 * HH; B2l = wb + 11 * HH;
        bias = bh;
    }

    const int brow = blockIdx.y * BM;
    const int bcol = blockIdx.x * BN;

    __shared__ __align__(16) u16 lds[4 * BM * BK];  // a_hi, a_lo, b_hi, b_lo = 32KB

    const int t = threadIdx.x;
    const int lane = t & 63;
    const int w = t >> 6;
    const int wrow = (w >> 1) * 64;
    const int wcol = (w & 1) * 64;
    const int lrow = lane & 15;
    const int lk16 = lane >> 4;

    f32x4 acc[4][4];
#pragma unroll
    for (int m = 0; m < 4; ++m)
#pragma unroll
        for (int n = 0; n < 4; ++n)
            acc[m][n] = (f32x4){0.f, 0.f, 0.f, 0.f};

    for (int ks = 0; ks < (2 * HDIM) / BK; ++ks) {
        const int kk = ks * BK;
        const u16 *Ah, *Al, *Bh, *Bl;
        int kcol;
        if (kk < HDIM) {
            Ah = up_hi; Al = up_lo; Bh = B1h; Bl = B1l; kcol = kk;
        } else {
            Ah = A2h; Al = A2l; Bh = B2h; Bl = B2l; kcol = kk - HDIM;
        }

        __syncthreads();
        stage_tile(Ah + (size_t)brow * HDIM + kcol, lds + 0 * 4096, t);
        stage_tile(Al + (size_t)brow * HDIM + kcol, lds + 1 * 4096, t);
        stage_tile(Bh + (size_t)bcol * HDIM + kcol, lds + 2 * 4096, t);
        stage_tile(Bl + (size_t)bcol * HDIM + kcol, lds + 3 * 4096, t);
        __syncthreads();

        bf16x8 afh[4], afl[4], bfh[4], bfl[4];
#pragma unroll
        for (int m = 0; m < 4; ++m) {
            int R = wrow + m * 16 + lrow;
            int off = R * 32 + (lk16 ^ ((R >> 1) & 3)) * 8;
            afh[m] = *(const bf16x8*)&lds[0 * 4096 + off];
            afl[m] = *(const bf16x8*)&lds[1 * 4096 + off];
        }
#pragma unroll
        for (int n = 0; n < 4; ++n) {
            int R = wcol + n * 16 + lrow;
            int off = R * 32 + (lk16 ^ ((R >> 1) & 3)) * 8;
            bfh[n] = *(const bf16x8*)&lds[2 * 4096 + off];
            bfl[n] = *(const bf16x8*)&lds[3 * 4096 + off];
        }
#pragma unroll
        for (int m = 0; m < 4; ++m)
#pragma unroll
            for (int n = 0; n < 4; ++n) {
                acc[m][n] = __builtin_amdgcn_mfma_f32_16x16x32_bf16(afh[m], bfh[n], acc[m][n], 0, 0, 0);
                acc[m][n] = __builtin_amdgcn_mfma_f32_16x16x32_bf16(afh[m], bfl[n], acc[m][n], 0, 0, 0);
                acc[m][n] = __builtin_amdgcn_mfma_f32_16x16x32_bf16(afl[m], bfh[n], acc[m][n], 0, 0, 0);
            }
    }

    // Epilogue. C/D layout (verified m89/m91): col = lane&15, row = (lane>>4)*4 + reg.
#pragma unroll
    for (int n = 0; n < 4; ++n) {
        int col = bcol + wcol + n * 16 + lrow;
        float b = bias[col];
#pragma unroll
        for (int m = 0; m < 4; ++m) {
#pragma unroll
            for (int j = 0; j < 4; ++j) {
                int row = brow + wrow + m * 16 + lk16 * 4 + j;
                size_t idx = (size_t)row * HDIM + col;
                float x = acc[m][n][j] + b;
                if (mode == 0) {
                    zbuf[idx] = 1.0f / (1.0f + __expf(-x));
                } else if (mode == 1) {
                    float r = 1.0f / (1.0f + __expf(-x));
                    float rh = r * hidden[idx];
                    u16 hh = f2bf(rh);
                    rh_hi_out[idx] = hh;
                    rh_lo_out[idx] = f2bf(rh - bf2f(hh));
                } else {
                    float e = __expf(2.0f * x);
                    float th = 1.0f - 2.0f / (e + 1.0f);
                    float zv = zbuf[idx];
                    float hd = hidden[idx];
                    out[idx] = (1.0f - zv) * hd + zv * th;
                }
            }
        }
    }
}

extern "C" void kernel_launch(void* const* d_in, const int* in_sizes, int n_in,
                              void* d_out, int out_size, void* d_ws, size_t ws_size,
                              hipStream_t stream) {
    const float* update = (const float*)d_in[0];
    const float* hidden = (const float*)d_in[1];
    const float* wz = (const float*)d_in[2];
    const float* uz = (const float*)d_in[3];
    const float* bz = (const float*)d_in[4];
    const float* wr = (const float*)d_in[5];
    const float* ur = (const float*)d_in[6];
    const float* br = (const float*)d_in[7];
    const float* wh = (const float*)d_in[8];
    const float* uh = (const float*)d_in[9];
    const float* bh = (const float*)d_in[10];
    float* out = (float*)d_out;

    const size_t NH = (size_t)NTOK * HDIM;  // 16M elems
    const size_t HH = (size_t)HDIM * HDIM;  // 1M elems

    u16* up_hi = (u16*)d_ws;
    u16* up_lo = up_hi + NH;
    u16* hid_hi = up_lo + NH;
    u16* hid_lo = hid_hi + NH;
    u16* rh_hi = hid_lo + NH;
    u16* rh_lo = rh_hi + NH;
    u16* wb = rh_lo + NH;  // 12 consecutive HxH arrays
    // total ws use: 12*NH + 24*HH bytes = 216 MB

    convert_split_kernel<<<2048, 256, 0, stream>>>(update, up_hi, up_lo, (int)(NH / 4));
    convert_split_kernel<<<2048, 256, 0, stream>>>(hidden, hid_hi, hid_lo, (int)(NH / 4));
    dim3 wgrid(256, 6, 1);
    convert_weights_kernel<<<wgrid, 256, 0, stream>>>(wz, uz, wr, ur, wh, uh,
                                                      wb, nullptr, (int)(HH / 4));

    dim3 blk(256, 1, 1);
    dim3 g1(HDIM / BN, NTOK / BM, 2);  // z (blockIdx.z=0) and r (blockIdx.z=1)
    gru_gemm_kernel<<<g1, blk, 0, stream>>>(
        up_hi, up_lo, hid_hi, hid_lo, rh_hi, rh_lo, wb,
        bz, br, bh, hidden, out /*zbuf*/, rh_hi, rh_lo, out, 0);

    dim3 g2(HDIM / BN, NTOK / BM, 1);  // h + final blend
    gru_gemm_kernel<<<g2, blk, 0, stream>>>(
        up_hi, up_lo, hid_hi, hid_lo, rh_hi, rh_lo, wb,
        bz, br, bh, hidden, out /*zbuf*/, rh_hi, rh_lo, out, 1);
}

// Round 11
// 750.750 us; speedup vs baseline: 1.2968x; 1.2968x over previous
//
#include <hip/hip_runtime.h>
#include <hip/hip_bf16.h>
#include <stdint.h>

using u16 = unsigned short;

#define HDIM 1024
#define NTOK 16384
#define BM 256
#define BN 256
#define BK 32
#define NKT ((2 * HDIM) / BK)  // 64 K-tiles over the concat-K axis

typedef __attribute__((ext_vector_type(4))) float f32x4;
typedef __attribute__((ext_vector_type(8))) short bf16x8;
typedef __attribute__((ext_vector_type(4))) float fvec4;
typedef __attribute__((ext_vector_type(4))) u16 us4;

typedef __attribute__((address_space(3))) uint8_t lds_u8;
typedef const __attribute__((address_space(1))) uint8_t gl_u8;

static __device__ __forceinline__ u16 f2bf(float f) {
    union { float f; uint32_t u; } a; a.f = f;
    uint32_t u = a.u;
    return (u16)((u + 0x7fffu + ((u >> 16) & 1u)) >> 16);
}
static __device__ __forceinline__ float bf2f(u16 h) {
    union { uint32_t u; float f; } a; a.u = ((uint32_t)h) << 16;
    return a.f;
}

// fp32 -> (bf16 hi, bf16 lo) split for update+hidden in one launch (y picks).
__global__ void convert_acts_kernel(const float* __restrict__ update,
                                    const float* __restrict__ hidden,
                                    u16* __restrict__ base, int n4) {
    const size_t NH = (size_t)NTOK * HDIM;
    const int m = blockIdx.y;  // 0: update, 1: hidden
    const float* src = m ? hidden : update;
    u16* hi = base + (size_t)(2 * m) * NH;
    u16* lo = base + (size_t)(2 * m + 1) * NH;
    int stride = gridDim.x * blockDim.x;
    for (int i = blockIdx.x * blockDim.x + threadIdx.x; i < n4; i += stride) {
        fvec4 v = ((const fvec4*)src)[i];
        us4 hv, lv;
#pragma unroll
        for (int j = 0; j < 4; ++j) {
            u16 h = f2bf(v[j]);
            hv[j] = h;
            lv[j] = f2bf(v[j] - bf2f(h));
        }
        ((us4*)hi)[i] = hv;
        ((us4*)lo)[i] = lv;
    }
}

// All six HxH weight splits in one launch; blockIdx.y selects the matrix.
__global__ void convert_weights_kernel(
    const float* __restrict__ wz, const float* __restrict__ uz,
    const float* __restrict__ wr, const float* __restrict__ ur,
    const float* __restrict__ wh, const float* __restrict__ uh,
    u16* __restrict__ dst_base, int n4) {
    const float* srcs[6] = {wz, uz, wr, ur, wh, uh};
    const int m = blockIdx.y;
    const float* src = srcs[m];
    const size_t HH = (size_t)HDIM * HDIM;
    u16* hi = dst_base + (size_t)(2 * m) * HH;
    u16* lo = dst_base + (size_t)(2 * m + 1) * HH;
    int stride = gridDim.x * blockDim.x;
    for (int i = blockIdx.x * blockDim.x + threadIdx.x; i < n4; i += stride) {
        fvec4 v = ((const fvec4*)src)[i];
        us4 hv, lv;
#pragma unroll
        for (int j = 0; j < 4; ++j) {
            u16 h = f2bf(v[j]);
            hv[j] = h;
            lv[j] = f2bf(v[j] - bf2f(h));
        }
        ((us4*)hi)[i] = hv;
        ((us4*)lo)[i] = lv;
    }
}

// 256x256 tile, BK=32, 16 waves (1024 thr), wave-tile 64x64, split-bf16 (3 MFMA/pair).
// Double-buffered LDS with prefetch-before-compute (T3-min): STAGE(next) issued
// before ds_read+MFMA(cur); __syncthreads() supplies the vmcnt(0)+barrier per tile.
// LDS per buffer: {A_hi, A_lo, B_hi, B_lo} each [256][32] u16 = 16KB -> 64KB; dbuf 128KB.
// Bank-conflict-free via source pre-swizzle + XOR'd read (0 conflicts on HW, round 2).
//  phase 0: blockIdx partitions N=2048 (z cols 0-1023 | r cols 1024-2047)
//  phase 1: h gate + final blend
__launch_bounds__(1024)
__global__ void gru_gemm_kernel(
    const u16* __restrict__ up_hi, const u16* __restrict__ up_lo,
    const u16* __restrict__ hid_hi, const u16* __restrict__ hid_lo,
    const u16* __restrict__ rh_hi_in, const u16* __restrict__ rh_lo_in,
    const u16* __restrict__ wb,   // 12 consecutive HxH bf16 arrays (hi/lo pairs)
    const float* __restrict__ bz, const float* __restrict__ br,
    const float* __restrict__ bh,
    const float* __restrict__ hidden,
    float* zbuf, u16* rh_hi_out, u16* rh_lo_out, float* out, int phase) {

    const size_t HH = (size_t)HDIM * HDIM;
    const int bid = blockIdx.x;
    const int bx = bid >> 6;      // column-tile major: 64 consecutive blocks share one B panel
    const int by = bid & 63;
    const int mode = (phase == 0) ? (bx < 4 ? 0 : 1) : 2;
    const int brow = by * BM;
    const int colg = (mode == 1) ? (bx - 4) * BN : bx * BN;

    const u16 *A2h, *A2l, *B1h, *B1l, *B2h, *B2l;
    const float* bias;
    if (mode == 0) {
        A2h = hid_hi; A2l = hid_lo;
        B1h = wb + 0 * HH; B1l = wb + 1 * HH; B2h = wb + 2 * HH; B2l = wb + 3 * HH;
        bias = bz;
    } else if (mode == 1) {
        A2h = hid_hi; A2l = hid_lo;
        B1h = wb + 4 * HH; B1l = wb + 5 * HH; B2h = wb + 6 * HH; B2l = wb + 7 * HH;
        bias = br;
    } else {
        A2h = rh_hi_in; A2l = rh_lo_in;
        B1h = wb + 8 * HH; B1l = wb + 9 * HH; B2h = wb + 10 * HH; B2l = wb + 11 * HH;
        bias = bh;
    }

    __shared__ __align__(16) u16 lds[2][4][BM * BK];  // 128 KB

    const int t = threadIdx.x;
    const int lane = t & 63;
    const int w = t >> 6;        // 0..15
    const int wy = w >> 2;       // 0..3 : row group (64 rows)
    const int wx = w & 3;        // 0..3 : col group (64 cols)
    const int lrow = lane & 15;
    const int lk16 = lane >> 4;

    // --- staging geometry: thread t -> (row = t>>2, 16B chunk = t&3), source chunk XOR-preswizzled
    const int srow = t >> 2;                       // 0..255
    const int scs = (t & 3) ^ ((srow >> 1) & 3);   // swizzled source chunk
    const size_t g_off = (size_t)srow * HDIM + (size_t)scs * 8;  // elems within a panel

    const u16* a1h = up_hi + (size_t)brow * HDIM + g_off;
    const u16* a1l = up_lo + (size_t)brow * HDIM + g_off;
    const u16* a2h = A2h + (size_t)brow * HDIM + g_off;
    const u16* a2l = A2l + (size_t)brow * HDIM + g_off;
    const u16* b1h = B1h + (size_t)colg * HDIM + g_off;
    const u16* b1l = B1l + (size_t)colg * HDIM + g_off;
    const u16* b2h = B2h + (size_t)colg * HDIM + g_off;
    const u16* b2l = B2l + (size_t)colg * HDIM + g_off;

    // --- LDS read byte-offsets (constant across K-steps; buffer adds 65536*buf)
    int soA[4], soB[4];
#pragma unroll
    for (int m = 0; m < 4; ++m) {
        int R = wy * 64 + m * 16 + lrow;
        soA[m] = (R * 32 + (lk16 ^ ((R >> 1) & 3)) * 8) * 2;
    }
#pragma unroll
    for (int n = 0; n < 4; ++n) {
        int R = wx * 64 + n * 16 + lrow;
        soB[n] = (R * 32 + (lk16 ^ ((R >> 1) & 3)) * 8) * 2;
    }

    f32x4 acc[4][4];
#pragma unroll
    for (int m = 0; m < 4; ++m)
#pragma unroll
        for (int n = 0; n < 4; ++n)
            acc[m][n] = (f32x4){0.f, 0.f, 0.f, 0.f};

    // stage K-tile kt into buffer buf (4 x global_load_lds width=16 per thread)
    auto STAGE = [&](int buf, int kt) {
        const int kk = kt * BK;
        const u16 *sah, *sal, *sbh, *sbl;
        int kc;
        if (kk < HDIM) { sah = a1h; sal = a1l; sbh = b1h; sbl = b1l; kc = kk; }
        else           { sah = a2h; sal = a2l; sbh = b2h; sbl = b2l; kc = kk - HDIM; }
        u16* d = &lds[buf][0][0] + (size_t)t * 8;
        __builtin_amdgcn_global_load_lds((gl_u8*)(sah + kc), (lds_u8*)(d + 0 * 8192), 16, 0, 0);
        __builtin_amdgcn_global_load_lds((gl_u8*)(sal + kc), (lds_u8*)(d + 1 * 8192), 16, 0, 0);
        __builtin_amdgcn_global_load_lds((gl_u8*)(sbh + kc), (lds_u8*)(d + 2 * 8192), 16, 0, 0);
        __builtin_amdgcn_global_load_lds((gl_u8*)(sbl + kc), (lds_u8*)(d + 3 * 8192), 16, 0, 0);
    };

    STAGE(0, 0);
    __syncthreads();

    for (int kt = 0; kt < NKT; ++kt) {
        const int nxt = (kt + 1 < NKT) ? kt + 1 : NKT - 1;  // tail: harmless redundant reload
        STAGE((kt + 1) & 1, nxt);   // issue-early: flies under this tile's MFMA phase

        const char* base = (const char*)&lds[kt & 1][0][0];
        bf16x8 bfh[4], bfl[4];
#pragma unroll
        for (int n = 0; n < 4; ++n) {
            bfh[n] = *(const bf16x8*)(base + 32768 + soB[n]);
            bfl[n] = *(const bf16x8*)(base + 49152 + soB[n]);
        }
#pragma unroll
        for (int m = 0; m < 4; ++m) {
            bf16x8 afh = *(const bf16x8*)(base + 0 + soA[m]);
            bf16x8 afl = *(const bf16x8*)(base + 16384 + soA[m]);
#pragma unroll
            for (int n = 0; n < 4; ++n) {
                acc[m][n] = __builtin_amdgcn_mfma_f32_16x16x32_bf16(afh, bfh[n], acc[m][n], 0, 0, 0);
                acc[m][n] = __builtin_amdgcn_mfma_f32_16x16x32_bf16(afh, bfl[n], acc[m][n], 0, 0, 0);
                acc[m][n] = __builtin_amdgcn_mfma_f32_16x16x32_bf16(afl, bfh[n], acc[m][n], 0, 0, 0);
            }
        }
        __syncthreads();  // vmcnt(0)+lgkmcnt(0)+barrier: next buffer ready, this one reusable
    }

    // Epilogue. C/D layout (verified m89/m91): col = lane&15, row = (lane>>4)*4 + reg.
    const int orow0 = brow + wy * 64;
    const int ocol0 = colg + wx * 64;
#pragma unroll
    for (int n = 0; n < 4; ++n) {
        const int col = ocol0 + n * 16 + lrow;
        const float b = bias[col];
#pragma unroll
        for (int m = 0; m < 4; ++m) {
#pragma unroll
            for (int j = 0; j < 4; ++j) {
                const int row = orow0 + m * 16 + lk16 * 4 + j;
                const size_t idx = (size_t)row * HDIM + col;
                const float x = acc[m][n][j] + b;
                if (mode == 0) {
                    zbuf[idx] = 1.0f / (1.0f + __expf(-x));
                } else if (mode == 1) {
                    float r = 1.0f / (1.0f + __expf(-x));
                    float rh = r * hidden[idx];
                    u16 hh = f2bf(rh);
                    rh_hi_out[idx] = hh;
                    rh_lo_out[idx] = f2bf(rh - bf2f(hh));
                } else {
                    float e = __expf(2.0f * x);
                    float th = 1.0f - 2.0f / (e + 1.0f);
                    float zv = zbuf[idx];
                    float hd = hidden[idx];
                    out[idx] = (1.0f - zv) * hd + zv * th;
                }
            }
        }
    }
}

extern "C" void kernel_launch(void* const* d_in, const int* in_sizes, int n_in,
                              void* d_out, int out_size, void* d_ws, size_t ws_size,
                              hipStream_t stream) {
    const float* update = (const float*)d_in[0];
    const float* hidden = (const float*)d_in[1];
    const float* wz = (const float*)d_in[2];
    const float* uz = (const float*)d_in[3];
    const float* bz = (const float*)d_in[4];
    const float* wr = (const float*)d_in[5];
    const float* ur = (const float*)d_in[6];
    const float* br = (const float*)d_in[7];
    const float* wh = (const float*)d_in[8];
    const float* uh = (const float*)d_in[9];
    const float* bh = (const float*)d_in[10];
    float* out = (float*)d_out;

    const size_t NH = (size_t)NTOK * HDIM;  // 16M elems
    const size_t HH = (size_t)HDIM * HDIM;  // 1M elems

    u16* acts = (u16*)d_ws;                 // up_hi, up_lo, hid_hi, hid_lo
    u16* up_hi = acts;
    u16* up_lo = up_hi + NH;
    u16* hid_hi = up_lo + NH;
    u16* hid_lo = hid_hi + NH;
    u16* rh_hi = hid_lo + NH;
    u16* rh_lo = rh_hi + NH;
    u16* wb = rh_lo + NH;                   // 12 consecutive HxH arrays
    // total ws use: 12*NH + 24*HH bytes = 216 MB (fits; verified round 2)

    dim3 agrid(2048, 2, 1);
    convert_acts_kernel<<<agrid, 256, 0, stream>>>(update, hidden, acts, (int)(NH / 4));
    dim3 wgrid(256, 6, 1);
    convert_weights_kernel<<<wgrid, 256, 0, stream>>>(wz, uz, wr, ur, wh, uh,
                                                      wb, (int)(HH / 4));

    dim3 blk(1024, 1, 1);
    // g1: z and r gates fused along N (8 col-tiles x 64 row-tiles = 512 blocks)
    gru_gemm_kernel<<<dim3(512, 1, 1), blk, 0, stream>>>(
        up_hi, up_lo, hid_hi, hid_lo, rh_hi, rh_lo, wb,
        bz, br, bh, hidden, out /*zbuf*/, rh_hi, rh_lo, out, 0);

    // g2: h gate + final blend (4 x 64 = 256 blocks, exactly one wave of CUs)
    gru_gemm_kernel<<<dim3(256, 1, 1), blk, 0, stream>>>(
        up_hi, up_lo, hid_hi, hid_lo, rh_hi, rh_lo, wb,
        bz, br, bh, hidden, out /*zbuf*/, rh_hi, rh_lo, out, 1);
}